// Round 1
// baseline (7079.895 us; speedup 1.0000x reference)
//
#include <hip/hip_runtime.h>

// LSTM (B=256, T=256, F=128, H=1024) + sigmoid + FC(1024->128).
// Strategy: persistent 256-WG kernel, one WG/CU. Per step t:
//   gates[B,4H] = [h_t | x_t] (K=1152, fp16) x W_cat^T (fp16, register-resident) + bias
//   per-lane i,f,g,o -> c,h update (fp32), h stored fp16 to ping-pong global buffer,
//   two-level grid barrier, repeat. Final: out = sigmoid(h_T) @ W_fc^T + b_fc.
//
// Tiling: WG (rg=wg>>5, cg=wg&31) owns batch rows rg*32..+31 and h-cols cg*32..+31
// (gate cols {n*1024 + cg*32 + 0..31}, n=0..3 = i,f,g,o). 4 waves split K (288 each),
// each wave holds its W slice in 288 VGPRs (72 x int4 frags). Cross-wave reduction in
// 64KB LDS. MFMA mfma_f32_32x32x16_f16: A lane: row=l&31,k=(l>>5)*8+j; B lane:
// col=l&31,k=(l>>5)*8+j; C lane/reg: col=l&31,row=(reg&3)+8*(reg>>2)+4*(l>>5) [m101].

typedef _Float16 f16x8 __attribute__((ext_vector_type(8)));
typedef float f32x16 __attribute__((ext_vector_type(16)));

#define WS_WP    0ull
#define WS_BIAS  9437184ull
#define WS_XT    (WS_BIAS + 16384ull)
#define WS_HB0   (WS_XT + 16777216ull)
#define WS_HB1   (WS_HB0 + 524288ull)
#define WS_SIGH  (WS_HB1 + 524288ull)
#define WS_BAR   (WS_SIGH + 1048576ull)

__device__ __forceinline__ unsigned short f2h(float f) {
  _Float16 h = (_Float16)f;
  return __builtin_bit_cast(unsigned short, h);
}

// Pack W_cat[4096][1152] (fp16) into per-(cg,wave,n,q,lane) MFMA B-fragments.
// flat idx i = ((((cg*4 + w)*4 + n)*18 + q)*64 + l)*8 + j
//   gcol = n*1024 + cg*32 + (l&31); k = w*288 + q*16 + (l>>5)*8 + j
//   k<1024 -> W_hh[gcol][k], else W_ih[gcol][k-1024]
__global__ void prep_pack(const float* __restrict__ W_ih, const float* __restrict__ W_hh,
                          const float* __restrict__ b_ih, const float* __restrict__ b_hh,
                          unsigned short* __restrict__ wp, float* __restrict__ bias) {
  unsigned i = blockIdx.x * 256u + threadIdx.x;
  if (i < 4718592u) {
    unsigned j = i & 7u;
    unsigned l = (i >> 3) & 63u;
    unsigned rest = i >> 9;
    unsigned q = rest % 18u;
    unsigned rest2 = rest / 18u;
    unsigned n = rest2 & 3u;
    unsigned rest3 = rest2 >> 2;
    unsigned w = rest3 & 3u;
    unsigned cg = rest3 >> 2;
    unsigned gcol = n * 1024u + cg * 32u + (l & 31u);
    unsigned k = w * 288u + q * 16u + (l >> 5) * 8u + j;
    float v = (k < 1024u) ? W_hh[(size_t)gcol * 1024u + k]
                          : W_ih[(size_t)gcol * 128u + (k - 1024u)];
    wp[i] = f2h(v);
  }
  if (i < 4096u) bias[i] = b_ih[i] + b_hh[i];
}

// x[B][T][F] fp32 -> xT[T][B][F] fp16 ; h0 -> fp16 hb0 ; zero barrier words.
__global__ void prep_misc(const float* __restrict__ x, const float* __restrict__ h0,
                          unsigned short* __restrict__ xT, unsigned short* __restrict__ hb0,
                          unsigned* __restrict__ bar) {
  unsigned i = blockIdx.x * 256u + threadIdx.x;
  if (i < 8388608u) {
    unsigned f = i & 127u;
    unsigned b = (i >> 7) & 255u;
    unsigned t = i >> 15;
    xT[i] = f2h(x[((size_t)b * 256u + t) * 128u + f]);
  }
  if (i < 262144u) hb0[i] = f2h(h0[i]);
  if (i < 640u) bar[i] = 0u;
}

__launch_bounds__(256, 1)
__global__ void lstm_main(const unsigned short* __restrict__ wp,
                          const float* __restrict__ bias,
                          const unsigned short* __restrict__ xT,
                          unsigned short* __restrict__ hb0,
                          unsigned short* __restrict__ hb1,
                          const float* __restrict__ c0,
                          float* __restrict__ sigh,
                          unsigned* __restrict__ bar) {
  extern __shared__ float red[];   // 64 KB reduce buffer
  const unsigned tid = threadIdx.x;
  const unsigned wg  = blockIdx.x;
  const unsigned w   = tid >> 6;       // wave 0..3 (K-quarter)
  const unsigned l   = tid & 63u;
  const unsigned rg  = wg >> 5;        // 0..7  batch row group (32 rows)
  const unsigned cg  = wg & 31u;       // 0..31 h-col group (32 cols)
  const unsigned lo5 = l & 31u;
  const unsigned hi  = l >> 5;

  // ---- register-resident W fragments (72 x int4 = 288 VGPRs) ----
  int4 Braw[4][18];
  {
    const int4* wpv = (const int4*)wp;
    const unsigned wbase = (cg * 4u + w) * 4608u;  // 4*18*64 int4 per (cg,w)
#pragma unroll
    for (int n = 0; n < 4; ++n) {
#pragma unroll
      for (int q = 0; q < 18; ++q) {
        Braw[n][q] = wpv[wbase + (unsigned)(n * 18 + q) * 64u + l];
      }
    }
  }

  float bias_v[4];
#pragma unroll
  for (int n = 0; n < 4; ++n) bias_v[n] = bias[(unsigned)n * 1024u + cg * 32u + lo5];

  // c state + output offsets: rows r = rg*32 + 8w + i + 4*hi, col = cg*32 + lo5
  const unsigned col = cg * 32u + lo5;
  float c_st[4];
  unsigned hoff[4], soff[4];
#pragma unroll
  for (int i = 0; i < 4; ++i) {
    unsigned r = rg * 32u + 8u * w + (unsigned)i + 4u * hi;
    soff[i] = r * 1024u + col;
    hoff[i] = soff[i] * 2u;
    c_st[i] = c0[soff[i]];
  }

  // A-operand addressing: row = rg*32 + lo5, k = w*288 + q*16 + hi*8 + j
  const unsigned arow = rg * 32u + lo5;
  const unsigned k0 = w * 288u;
  const unsigned nqh = (w == 3u) ? 10u : 18u;  // q's in h-region (k<1024)
  const unsigned hbyte = (arow * 1024u + k0 + hi * 8u) * 2u;
  unsigned xb = (arow * 128u + hi * 8u) * 2u;  // xT byte offset for t=0 (+65536/step)

  const char* hrd = (const char*)hb0;
  char* hwr = (char*)hb1;
  const char* xbase = (const char*)xT;

  for (unsigned t = 0; t < 256u; ++t) {
    const char* xb_t = xbase + xb;
    f32x16 acc[4] = {};

    int4 ar[4];
#pragma unroll
    for (int q = 0; q < 4; ++q)   // first 4 always in h-region (nqh >= 10)
      ar[q] = *(const int4*)(hrd + hbyte + (unsigned)q * 32u);

#pragma unroll
    for (int q = 0; q < 18; ++q) {
      f16x8 a = __builtin_bit_cast(f16x8, ar[q & 3]);
      if (q + 4 < 18) {
        int pq = q + 4;
        ar[q & 3] = (pq < (int)nqh)
            ? *(const int4*)(hrd + hbyte + (unsigned)pq * 32u)
            : *(const int4*)(xb_t + (unsigned)(pq - (int)nqh) * 32u);
      }
      acc[0] = __builtin_amdgcn_mfma_f32_32x32x16_f16(a, __builtin_bit_cast(f16x8, Braw[0][q]), acc[0], 0, 0, 0);
      acc[1] = __builtin_amdgcn_mfma_f32_32x32x16_f16(a, __builtin_bit_cast(f16x8, Braw[1][q]), acc[1], 0, 0, 0);
      acc[2] = __builtin_amdgcn_mfma_f32_32x32x16_f16(a, __builtin_bit_cast(f16x8, Braw[2][q]), acc[2], 0, 0, 0);
      acc[3] = __builtin_amdgcn_mfma_f32_32x32x16_f16(a, __builtin_bit_cast(f16x8, Braw[3][q]), acc[3], 0, 0, 0);
    }

    // ---- cross-wave K reduction via LDS ----
    float4* redv = (float4*)red;
#pragma unroll
    for (int n = 0; n < 4; ++n) {
#pragma unroll
      for (int c = 0; c < 4; ++c) {
        float4 v;
        v.x = acc[n][4 * c + 0]; v.y = acc[n][4 * c + 1];
        v.z = acc[n][4 * c + 2]; v.w = acc[n][4 * c + 3];
        redv[((w * 4u + (unsigned)n) * 4u + (unsigned)c) * 64u + l] = v;
      }
    }
    __syncthreads();

    float gv[4][4];
#pragma unroll
    for (int n = 0; n < 4; ++n) {
      float4 s; s.x = bias_v[n]; s.y = bias_v[n]; s.z = bias_v[n]; s.w = bias_v[n];
#pragma unroll
      for (int wo = 0; wo < 4; ++wo) {
        float4 v = redv[(((unsigned)wo * 4u + (unsigned)n) * 4u + w) * 64u + l];
        s.x += v.x; s.y += v.y; s.z += v.z; s.w += v.w;
      }
      gv[n][0] = s.x; gv[n][1] = s.y; gv[n][2] = s.z; gv[n][3] = s.w;
    }

    // ---- per-lane LSTM cell update (rows 8w+i+4hi) ----
    const bool last = (t == 255u);
#pragma unroll
    for (int i = 0; i < 4; ++i) {
      float ig = 1.f / (1.f + __expf(-gv[0][i]));
      float fg = 1.f / (1.f + __expf(-gv[1][i]));
      float gg = tanhf(gv[2][i]);
      float og = 1.f / (1.f + __expf(-gv[3][i]));
      float cc = fg * c_st[i] + ig * gg;
      c_st[i] = cc;
      float hh = og * tanhf(cc);
      *(unsigned short*)(hwr + hoff[i]) = f2h(hh);
      if (last) sigh[soff[i]] = 1.f / (1.f + __expf(-hh));
    }

    // ---- two-level grid barrier (8 groups of 32 + master + epoch) ----
    __syncthreads();
    if (tid == 0) {
      __threadfence();  // release h-writes (L2 wb) before arrive
      unsigned grp = wg & 7u;
      unsigned a = __hip_atomic_fetch_add(&bar[grp * 64u], 1u, __ATOMIC_RELAXED, __HIP_MEMORY_SCOPE_AGENT);
      if (a == 31u) {
        unsigned m = __hip_atomic_fetch_add(&bar[512u], 1u, __ATOMIC_ACQ_REL, __HIP_MEMORY_SCOPE_AGENT);
        if (m == 7u) {
#pragma unroll
          for (int i2 = 0; i2 < 8; ++i2)
            __hip_atomic_store(&bar[(unsigned)i2 * 64u], 0u, __ATOMIC_RELAXED, __HIP_MEMORY_SCOPE_AGENT);
          __hip_atomic_store(&bar[512u], 0u, __ATOMIC_RELAXED, __HIP_MEMORY_SCOPE_AGENT);
          __hip_atomic_fetch_add(&bar[576u], 1u, __ATOMIC_RELEASE, __HIP_MEMORY_SCOPE_AGENT);
        }
      }
      while (__hip_atomic_load(&bar[576u], __ATOMIC_ACQUIRE, __HIP_MEMORY_SCOPE_AGENT) < t + 1u) {
        __builtin_amdgcn_s_sleep(2);
      }
      __threadfence();  // acquire: invalidate stale L1/L2 before next step's h reads
    }
    __syncthreads();

    const char* tmp = hrd; hrd = hwr; hwr = (char*)tmp;
    xb += 65536u;
  }
}

// out[b][o] = b_fc[o] + sum_k sigh[b][k] * W_fc[o][k]
__global__ void final_fc(const float* __restrict__ sigh, const float* __restrict__ W_fc,
                         const float* __restrict__ b_fc, float* __restrict__ out) {
  unsigned b = blockIdx.x;
  unsigned o = threadIdx.x;
  const float* hrow = sigh + (size_t)b * 1024u;
  const float* wrow = W_fc + (size_t)o * 1024u;
  float acc = b_fc[o];
#pragma unroll 8
  for (unsigned k = 0; k < 1024u; k += 4u) {
    float4 hv = *(const float4*)(hrow + k);
    float4 wv = *(const float4*)(wrow + k);
    acc += hv.x * wv.x + hv.y * wv.y + hv.z * wv.z + hv.w * wv.w;
  }
  out[b * 128u + o] = acc;
}

extern "C" void kernel_launch(void* const* d_in, const int* in_sizes, int n_in,
                              void* d_out, int out_size, void* d_ws, size_t ws_size,
                              hipStream_t stream) {
  (void)in_sizes; (void)n_in; (void)out_size; (void)ws_size;
  const float* x    = (const float*)d_in[0];
  const float* h0   = (const float*)d_in[1];
  const float* c0   = (const float*)d_in[2];
  const float* W_ih = (const float*)d_in[3];
  const float* W_hh = (const float*)d_in[4];
  const float* b_ih = (const float*)d_in[5];
  const float* b_hh = (const float*)d_in[6];
  const float* W_fc = (const float*)d_in[7];
  const float* b_fc = (const float*)d_in[8];

  char* ws = (char*)d_ws;
  unsigned short* wp   = (unsigned short*)(ws + WS_WP);
  float*          bias = (float*)(ws + WS_BIAS);
  unsigned short* xT   = (unsigned short*)(ws + WS_XT);
  unsigned short* hb0  = (unsigned short*)(ws + WS_HB0);
  unsigned short* hb1  = (unsigned short*)(ws + WS_HB1);
  float*          sigh = (float*)(ws + WS_SIGH);
  unsigned*       bar  = (unsigned*)(ws + WS_BAR);
  float*          out  = (float*)d_out;

  prep_pack<<<18432, 256, 0, stream>>>(W_ih, W_hh, b_ih, b_hh, wp, bias);
  prep_misc<<<32768, 256, 0, stream>>>(x, h0, xT, hb0, bar);
  lstm_main<<<256, 256, 65536, stream>>>(wp, bias, xT, hb0, hb1, c0, sigh, bar);
  final_fc<<<256, 128, 0, stream>>>(sigh, W_fc, b_fc, out);
}

// Round 3
// 2055.622 us; speedup vs baseline: 3.4442x; 3.4442x over previous
//
#include <hip/hip_runtime.h>

// LSTM (B=256, T=256, F=128, H=1024) + sigmoid + FC(1024->128).
// Persistent 256-WG kernel, one WG/CU. Per step t:
//   gates[B,4H] = [h_t | x_t] (K=1152, fp16) x W_cat^T (fp16, register-resident) + bias
//   per-lane i,f,g,o -> c,h update (fp32). h tile staged to LDS then stored as
//   coalesced 8B AGENT-scope relaxed atomic stores (write-through to the coherence
//   point, no dirty L2 lines); consumers re-read h via AGENT-scope relaxed atomic
//   8B loads (bypass stale L1/L2). Cohort-local monotonic barrier: 8 independent
//   groups of 32 WGs (one per batch row-group), all-relaxed agent atomics, zero
//   cache-maintenance fences. NO inline asm anywhere - compiler owns all waitcnts.
//
// Tiling: WG (rg=wg>>5, cg=wg&31) owns batch rows rg*32..+31 and h-cols cg*32..+31
// (gate cols {n*1024 + cg*32 + 0..31}, n=0..3 = i,f,g,o). 4 waves split K (288 each),
// each wave holds its W slice in 288 VGPRs (72 x int4 frags). Cross-wave reduction in
// 64KB LDS. MFMA mfma_f32_32x32x16_f16: A lane: row=l&31,k=(l>>5)*8+j; B lane:
// col=l&31,k=(l>>5)*8+j; C lane/reg: col=l&31,row=(reg&3)+8*(reg>>2)+4*(l>>5) [m101].
// Only the 32 WGs sharing rg exchange data -> cohort barrier, not grid barrier.

typedef _Float16 f16x8 __attribute__((ext_vector_type(8)));
typedef float f32x16 __attribute__((ext_vector_type(16)));
typedef unsigned long long u64;
struct U128 { u64 a, b; };

#define SCOPE_AGENT __HIP_MEMORY_SCOPE_AGENT

#define WS_WP    0ull
#define WS_BIAS  9437184ull
#define WS_XT    (WS_BIAS + 16384ull)
#define WS_HB0   (WS_XT + 16777216ull)
#define WS_HB1   (WS_HB0 + 524288ull)
#define WS_SIGH  (WS_HB1 + 524288ull)
#define WS_BAR   (WS_SIGH + 1048576ull)

__device__ __forceinline__ unsigned short f2h(float f) {
  _Float16 h = (_Float16)f;
  return __builtin_bit_cast(unsigned short, h);
}

// Pack W_cat[4096][1152] (fp16) into per-(cg,wave,n,q,lane) MFMA B-fragments.
// flat idx i = ((((cg*4 + w)*4 + n)*18 + q)*64 + l)*8 + j
//   gcol = n*1024 + cg*32 + (l&31); k = w*288 + q*16 + (l>>5)*8 + j
//   k<1024 -> W_hh[gcol][k], else W_ih[gcol][k-1024]
__global__ void prep_pack(const float* __restrict__ W_ih, const float* __restrict__ W_hh,
                          const float* __restrict__ b_ih, const float* __restrict__ b_hh,
                          unsigned short* __restrict__ wp, float* __restrict__ bias) {
  unsigned i = blockIdx.x * 256u + threadIdx.x;
  if (i < 4718592u) {
    unsigned j = i & 7u;
    unsigned l = (i >> 3) & 63u;
    unsigned rest = i >> 9;
    unsigned q = rest % 18u;
    unsigned rest2 = rest / 18u;
    unsigned n = rest2 & 3u;
    unsigned rest3 = rest2 >> 2;
    unsigned w = rest3 & 3u;
    unsigned cg = rest3 >> 2;
    unsigned gcol = n * 1024u + cg * 32u + (l & 31u);
    unsigned k = w * 288u + q * 16u + (l >> 5) * 8u + j;
    float v = (k < 1024u) ? W_hh[(size_t)gcol * 1024u + k]
                          : W_ih[(size_t)gcol * 128u + (k - 1024u)];
    wp[i] = f2h(v);
  }
  if (i < 4096u) bias[i] = b_ih[i] + b_hh[i];
}

// x[B][T][F] fp32 -> xT[T][B][F] fp16 ; h0 -> fp16 hb0 ; zero barrier words.
__global__ void prep_misc(const float* __restrict__ x, const float* __restrict__ h0,
                          unsigned short* __restrict__ xT, unsigned short* __restrict__ hb0,
                          unsigned* __restrict__ bar) {
  unsigned i = blockIdx.x * 256u + threadIdx.x;
  if (i < 8388608u) {
    unsigned f = i & 127u;
    unsigned b = (i >> 7) & 255u;
    unsigned t = i >> 15;
    xT[i] = f2h(x[((size_t)b * 256u + t) * 128u + f]);
  }
  if (i < 262144u) hb0[i] = f2h(h0[i]);
  if (i < 640u) bar[i] = 0u;
}

__launch_bounds__(256, 1)
__global__ void lstm_main(const unsigned short* __restrict__ wp,
                          const float* __restrict__ bias,
                          const unsigned short* __restrict__ xT,
                          unsigned short* __restrict__ hb0,
                          unsigned short* __restrict__ hb1,
                          const float* __restrict__ c0,
                          float* __restrict__ sigh,
                          unsigned* __restrict__ bar) {
  extern __shared__ char lds[];
  float4* redv = (float4*)lds;                            // 64 KB reduce buffer
  unsigned short* hst = (unsigned short*)(lds + 65536);   // 2 KB h staging tile

  const unsigned tid = threadIdx.x;
  const unsigned wg  = blockIdx.x;
  const unsigned w   = tid >> 6;       // wave 0..3 (K-quarter)
  const unsigned l   = tid & 63u;
  const unsigned rg  = wg >> 5;        // 0..7  batch row group (32 rows) = cohort id
  const unsigned cg  = wg & 31u;       // 0..31 h-col group (32 cols)
  const unsigned lo5 = l & 31u;
  const unsigned hi  = l >> 5;

  // ---- register-resident W fragments (72 x int4 = 288 VGPRs) ----
  int4 Braw[4][18];
  {
    const int4* wpv = (const int4*)wp;
    const unsigned wbase = (cg * 4u + w) * 4608u;  // 4*18*64 int4 per (cg,w)
#pragma unroll
    for (int n = 0; n < 4; ++n) {
#pragma unroll
      for (int q = 0; q < 18; ++q) {
        Braw[n][q] = wpv[wbase + (unsigned)(n * 18 + q) * 64u + l];
      }
    }
  }

  float bias_v[4];
#pragma unroll
  for (int n = 0; n < 4; ++n) bias_v[n] = bias[(unsigned)n * 1024u + cg * 32u + lo5];

  // c state + output offsets: rows r = rg*32 + 8w + i + 4*hi, col = cg*32 + lo5
  const unsigned col = cg * 32u + lo5;
  float c_st[4];
  unsigned soff[4];
#pragma unroll
  for (int i = 0; i < 4; ++i) {
    unsigned r = rg * 32u + 8u * w + (unsigned)i + 4u * hi;
    soff[i] = r * 1024u + col;
    c_st[i] = c0[soff[i]];
  }

  // A-operand addressing: row = rg*32 + lo5, k = w*288 + q*16 + hi*8 + j
  const unsigned arow = rg * 32u + lo5;
  const unsigned k0 = w * 288u;
  const int nqh = (w == 3u) ? 10 : 18;  // q's in h-region (k<1024)
  const unsigned hbyte = (arow * 1024u + k0 + hi * 8u) * 2u;
  unsigned xb = (arow * 128u + hi * 8u) * 2u;  // xT byte offset for t=0 (+65536/step)

  const char* hrd = (const char*)hb0;
  char* hwr = (char*)hb1;
  const char* xbase = (const char*)xT;
  unsigned* cbar = &bar[rg * 64u];     // cohort monotonic counter (own cache line)

  // h store-out addressing (after LDS staging): 256 threads x 8B
  const unsigned srow = tid >> 3;      // 0..31 local row
  const unsigned sseg = tid & 7u;      // 0..7  4-col segment
  const unsigned sgoff = (((rg * 32u + srow) * 1024u) + cg * 32u + sseg * 4u) * 2u;

  for (unsigned t = 0; t < 256u; ++t) {
    const char* xb_t = xbase + xb;

    // ---- preload all A fragments; h via agent-coherent 8B loads, x plain ----
    int4 ar[18];
#pragma unroll
    for (int q = 0; q < 18; ++q) {
      if (q < nqh) {
        const char* s = hrd + hbyte + (unsigned)q * 32u;
        U128 p;
        p.a = __hip_atomic_load((const u64*)s,        __ATOMIC_RELAXED, SCOPE_AGENT);
        p.b = __hip_atomic_load((const u64*)(s + 8),  __ATOMIC_RELAXED, SCOPE_AGENT);
        ar[q] = __builtin_bit_cast(int4, p);
      } else {
        ar[q] = *(const int4*)(xb_t + (unsigned)(q - nqh) * 32u);
      }
    }

    f32x16 acc[4] = {};
#pragma unroll
    for (int q = 0; q < 18; ++q) {
      f16x8 a = __builtin_bit_cast(f16x8, ar[q]);
      acc[0] = __builtin_amdgcn_mfma_f32_32x32x16_f16(a, __builtin_bit_cast(f16x8, Braw[0][q]), acc[0], 0, 0, 0);
      acc[1] = __builtin_amdgcn_mfma_f32_32x32x16_f16(a, __builtin_bit_cast(f16x8, Braw[1][q]), acc[1], 0, 0, 0);
      acc[2] = __builtin_amdgcn_mfma_f32_32x32x16_f16(a, __builtin_bit_cast(f16x8, Braw[2][q]), acc[2], 0, 0, 0);
      acc[3] = __builtin_amdgcn_mfma_f32_32x32x16_f16(a, __builtin_bit_cast(f16x8, Braw[3][q]), acc[3], 0, 0, 0);
    }

    // ---- cross-wave K reduction via LDS ----
#pragma unroll
    for (int n = 0; n < 4; ++n) {
#pragma unroll
      for (int c = 0; c < 4; ++c) {
        float4 v;
        v.x = acc[n][4 * c + 0]; v.y = acc[n][4 * c + 1];
        v.z = acc[n][4 * c + 2]; v.w = acc[n][4 * c + 3];
        redv[((w * 4u + (unsigned)n) * 4u + (unsigned)c) * 64u + l] = v;
      }
    }
    __syncthreads();

    float gv[4][4];
#pragma unroll
    for (int n = 0; n < 4; ++n) {
      float4 s; s.x = bias_v[n]; s.y = bias_v[n]; s.z = bias_v[n]; s.w = bias_v[n];
#pragma unroll
      for (int wo = 0; wo < 4; ++wo) {
        float4 v = redv[(((unsigned)wo * 4u + (unsigned)n) * 4u + w) * 64u + l];
        s.x += v.x; s.y += v.y; s.z += v.z; s.w += v.w;
      }
      gv[n][0] = s.x; gv[n][1] = s.y; gv[n][2] = s.z; gv[n][3] = s.w;
    }

    // ---- per-lane LSTM cell update (rows 8w+i+4hi); stage h to LDS ----
    const bool last = (t == 255u);
#pragma unroll
    for (int i = 0; i < 4; ++i) {
      float ig = 1.f / (1.f + __expf(-gv[0][i]));
      float fg = 1.f / (1.f + __expf(-gv[1][i]));
      float gg = tanhf(gv[2][i]);
      float og = 1.f / (1.f + __expf(-gv[3][i]));
      float cc = fg * c_st[i] + ig * gg;
      c_st[i] = cc;
      float hh = og * tanhf(cc);
      hst[(8u * w + (unsigned)i + 4u * hi) * 32u + lo5] = f2h(hh);
      if (last) sigh[soff[i]] = 1.f / (1.f + __expf(-hh));
    }

    if (!last) {
      __syncthreads();  // h staging tile complete
      // ---- coalesced 8B agent-coherent h store-out ----
      {
        u64 v = *(const u64*)(hst + srow * 32u + sseg * 4u);
        __hip_atomic_store((u64*)(hwr + sgoff), v, __ATOMIC_RELAXED, SCOPE_AGENT);
      }
      // __syncthreads lowering waits vmcnt(0): every thread's store is ACKed at
      // the coherence point before any thread passes this barrier.
      __syncthreads();
      // ---- cohort barrier: monotonic counter, all-relaxed, no fences ----
      if (tid == 0) {
        __hip_atomic_fetch_add(cbar, 1u, __ATOMIC_RELAXED, SCOPE_AGENT);
        const unsigned target = 32u * (t + 1u);
        while (__hip_atomic_load(cbar, __ATOMIC_RELAXED, SCOPE_AGENT) < target) {
          __builtin_amdgcn_s_sleep(1);
        }
      }
      __syncthreads();
    }

    const char* tmp = hrd; hrd = hwr; hwr = (char*)tmp;
    xb += 65536u;
  }
}

// out[b][o] = b_fc[o] + sum_k sigh[b][k] * W_fc[o][k]
__global__ void final_fc(const float* __restrict__ sigh, const float* __restrict__ W_fc,
                         const float* __restrict__ b_fc, float* __restrict__ out) {
  unsigned b = blockIdx.x;
  unsigned o = threadIdx.x;
  const float* hrow = sigh + (size_t)b * 1024u;
  const float* wrow = W_fc + (size_t)o * 1024u;
  float acc = b_fc[o];
#pragma unroll 8
  for (unsigned k = 0; k < 1024u; k += 4u) {
    float4 hv = *(const float4*)(hrow + k);
    float4 wv = *(const float4*)(wrow + k);
    acc += hv.x * wv.x + hv.y * wv.y + hv.z * wv.z + hv.w * wv.w;
  }
  out[b * 128u + o] = acc;
}

extern "C" void kernel_launch(void* const* d_in, const int* in_sizes, int n_in,
                              void* d_out, int out_size, void* d_ws, size_t ws_size,
                              hipStream_t stream) {
  (void)in_sizes; (void)n_in; (void)out_size; (void)ws_size;
  const float* x    = (const float*)d_in[0];
  const float* h0   = (const float*)d_in[1];
  const float* c0   = (const float*)d_in[2];
  const float* W_ih = (const float*)d_in[3];
  const float* W_hh = (const float*)d_in[4];
  const float* b_ih = (const float*)d_in[5];
  const float* b_hh = (const float*)d_in[6];
  const float* W_fc = (const float*)d_in[7];
  const float* b_fc = (const float*)d_in[8];

  char* ws = (char*)d_ws;
  unsigned short* wp   = (unsigned short*)(ws + WS_WP);
  float*          bias = (float*)(ws + WS_BIAS);
  unsigned short* xT   = (unsigned short*)(ws + WS_XT);
  unsigned short* hb0  = (unsigned short*)(ws + WS_HB0);
  unsigned short* hb1  = (unsigned short*)(ws + WS_HB1);
  float*          sigh = (float*)(ws + WS_SIGH);
  unsigned*       bar  = (unsigned*)(ws + WS_BAR);
  float*          out  = (float*)d_out;

  prep_pack<<<18432, 256, 0, stream>>>(W_ih, W_hh, b_ih, b_hh, wp, bias);
  prep_misc<<<32768, 256, 0, stream>>>(x, h0, xT, hb0, bar);
  lstm_main<<<256, 256, 67584, stream>>>(wp, bias, xT, hb0, hb1, c0, sigh, bar);
  final_fc<<<256, 128, 0, stream>>>(sigh, W_fc, b_fc, out);
}

// Round 5
// 1946.184 us; speedup vs baseline: 3.6378x; 1.0562x over previous
//
#include <hip/hip_runtime.h>

// LSTM (B=256, T=256, F=128, H=1024) + sigmoid + FC(1024->128).
// Persistent 256-WG kernel. Per step t:
//   gates[B,4H] = [h_t | x_t] (fp16) x W_cat^T (fp16, register-resident) + bias
//   per-lane i,f,g,o -> c,h update (fp32). h exchanged through the coherence
//   point (MALL) with AGENT-scope relaxed atomics (proven R3 design).
// Barrier (RMW-free): cohort rg has 32 epoch flags on ONE 128B line. Arrival =
// tid0 stores t+1 to flags[cg] (independent words, no RMW serialization).
// Poll = wave 0 only: lanes 0..31 load all 32 flags as one coalesced 128B
// request, __all(flag >= t+1). Monotonic epochs -> no reset, replay-safe.
//
// Tiling: WG (rg=wg>>5, cg=wg&31) owns batch rows rg*32..+31 and h-cols
// cg*32..+31 (gate cols n*1024+cg*32+0..31, n=0..3). 4 waves split K uniformly:
// wave w owns h-K [w*256, w*256+256) (16 chunks) + x-K [w*32, w*32+32)
// (2 chunks). Cross-wave reduction in 64KB LDS. MFMA mfma_f32_32x32x16_f16,
// C layout: col=lane&31, row=(reg&3)+8*(reg>>2)+4*(lane>>5) [m101].
// Next-step x fragments prefetched before the barrier (plain cached loads).

typedef _Float16 f16x8 __attribute__((ext_vector_type(8)));
typedef float f32x16 __attribute__((ext_vector_type(16)));
typedef unsigned long long u64;
struct U128 { u64 a, b; };

#define SCOPE_AGENT __HIP_MEMORY_SCOPE_AGENT

#define WS_WP    0ull
#define WS_BIAS  9437184ull
#define WS_XT    (WS_BIAS + 16384ull)
#define WS_HB0   (WS_XT + 16777216ull)
#define WS_HB1   (WS_HB0 + 524288ull)
#define WS_SIGH  (WS_HB1 + 524288ull)
#define WS_BAR   (WS_SIGH + 1048576ull)

__device__ __forceinline__ unsigned short f2h(float f) {
  _Float16 h = (_Float16)f;
  return __builtin_bit_cast(unsigned short, h);
}

// Pack W_cat[4096][1152] (fp16) into per-(cg,wave,n,q,lane) MFMA B-fragments.
// flat idx i = ((((cg*4 + w)*4 + n)*18 + q)*64 + l)*8 + j
//   gcol = n*1024 + cg*32 + (l&31)
//   q<16:  k = w*256 + q*16 + (l>>5)*8 + j          (h region, W_hh[gcol][k])
//   q>=16: f = w*32 + (q-16)*16 + (l>>5)*8 + j      (x region, W_ih[gcol][f])
__global__ void prep_pack(const float* __restrict__ W_ih, const float* __restrict__ W_hh,
                          const float* __restrict__ b_ih, const float* __restrict__ b_hh,
                          unsigned short* __restrict__ wp, float* __restrict__ bias) {
  unsigned i = blockIdx.x * 256u + threadIdx.x;
  if (i < 4718592u) {
    unsigned j = i & 7u;
    unsigned l = (i >> 3) & 63u;
    unsigned rest = i >> 9;
    unsigned q = rest % 18u;
    unsigned rest2 = rest / 18u;
    unsigned n = rest2 & 3u;
    unsigned rest3 = rest2 >> 2;
    unsigned w = rest3 & 3u;
    unsigned cg = rest3 >> 2;
    unsigned gcol = n * 1024u + cg * 32u + (l & 31u);
    unsigned khi = (l >> 5) * 8u + j;
    float v;
    if (q < 16u) {
      unsigned k = w * 256u + q * 16u + khi;
      v = W_hh[(size_t)gcol * 1024u + k];
    } else {
      unsigned k = w * 32u + (q - 16u) * 16u + khi;
      v = W_ih[(size_t)gcol * 128u + k];
    }
    wp[i] = f2h(v);
  }
  if (i < 4096u) bias[i] = b_ih[i] + b_hh[i];
}

// x[B][T][F] fp32 -> xT[T][B][F] fp16 ; h0 -> fp16 hb0 ; zero barrier words.
__global__ void prep_misc(const float* __restrict__ x, const float* __restrict__ h0,
                          unsigned short* __restrict__ xT, unsigned short* __restrict__ hb0,
                          unsigned* __restrict__ bar) {
  unsigned i = blockIdx.x * 256u + threadIdx.x;
  if (i < 8388608u) {
    unsigned f = i & 127u;
    unsigned b = (i >> 7) & 255u;
    unsigned t = i >> 15;
    xT[i] = f2h(x[((size_t)b * 256u + t) * 128u + f]);
  }
  if (i < 262144u) hb0[i] = f2h(h0[i]);
  if (i < 768u) bar[i] = 0u;
}

__launch_bounds__(256, 1)
__global__ void lstm_main(const unsigned short* __restrict__ wp,
                          const float* __restrict__ bias,
                          const unsigned short* __restrict__ xT,
                          unsigned short* __restrict__ hb0,
                          unsigned short* __restrict__ hb1,
                          const float* __restrict__ c0,
                          float* __restrict__ sigh,
                          unsigned* __restrict__ bar) {
  extern __shared__ char lds[];
  float4* redv = (float4*)lds;                            // 64 KB reduce buffer
  unsigned short* hst = (unsigned short*)(lds + 65536);   // 2 KB h staging tile

  const unsigned tid = threadIdx.x;
  const unsigned wg  = blockIdx.x;
  const unsigned w   = tid >> 6;       // wave 0..3 (K-part)
  const unsigned l   = tid & 63u;
  const unsigned rg  = wg >> 5;        // 0..7  batch row group (32 rows) = cohort
  const unsigned cg  = wg & 31u;       // 0..31 h-col group (32 cols)
  const unsigned lo5 = l & 31u;
  const unsigned hi  = l >> 5;

  // ---- register-resident W fragments (72 x int4 = 288 VGPRs) ----
  int4 Braw[4][18];
  {
    const int4* wpv = (const int4*)wp;
    const unsigned wbase = (cg * 4u + w) * 4608u;  // 4*18*64 int4 per (cg,w)
#pragma unroll
    for (int n = 0; n < 4; ++n) {
#pragma unroll
      for (int q = 0; q < 18; ++q) {
        Braw[n][q] = wpv[wbase + (unsigned)(n * 18 + q) * 64u + l];
      }
    }
  }

  float bias_v[4];
#pragma unroll
  for (int n = 0; n < 4; ++n) bias_v[n] = bias[(unsigned)n * 1024u + cg * 32u + lo5];

  // c state + output offsets: rows r = rg*32 + 8w + i + 4*hi, col = cg*32 + lo5
  const unsigned col = cg * 32u + lo5;
  float c_st[4];
  unsigned soff[4];
#pragma unroll
  for (int i = 0; i < 4; ++i) {
    unsigned r = rg * 32u + 8u * w + (unsigned)i + 4u * hi;
    soff[i] = r * 1024u + col;
    c_st[i] = c0[soff[i]];
  }

  // A-operand addressing: row = rg*32 + lo5
  //   h chunks q=0..15: k = w*256 + q*16 + hi*8 + j
  //   x chunks q=16,17: f = w*32 + (q-16)*16 + hi*8 + j
  const unsigned arow = rg * 32u + lo5;
  const unsigned hbyte = (arow * 1024u + w * 256u + hi * 8u) * 2u;
  unsigned xb = (arow * 128u + w * 32u + hi * 8u) * 2u;  // + 65536/step

  const char* hrd = (const char*)hb0;
  char* hwr = (char*)hb1;
  const char* xbase = (const char*)xT;
  unsigned* flags = &bar[rg * 32u];    // 32 x 4B epoch flags, one 128B line

  // h store-out addressing (after LDS staging): 256 threads x 8B
  const unsigned srow = tid >> 3;      // 0..31 local row
  const unsigned sseg = tid & 7u;      // 0..7  4-col segment
  const unsigned sgoff = (((rg * 32u + srow) * 1024u) + cg * 32u + sseg * 4u) * 2u;

  // prefetch x fragments for t=0 (plain cached loads)
  int4 xr[2];
  xr[0] = *(const int4*)(xbase + xb);
  xr[1] = *(const int4*)(xbase + xb + 32u);

  for (unsigned t = 0; t < 256u; ++t) {
    // ---- 16 h fragment loads (agent-coherent 8B pairs -> MALL) ----
    int4 ah[16];
#pragma unroll
    for (int q = 0; q < 16; ++q) {
      const char* s = hrd + hbyte + (unsigned)q * 32u;
      U128 p;
      p.a = __hip_atomic_load((const u64*)s,       __ATOMIC_RELAXED, SCOPE_AGENT);
      p.b = __hip_atomic_load((const u64*)(s + 8), __ATOMIC_RELAXED, SCOPE_AGENT);
      ah[q] = __builtin_bit_cast(int4, p);
    }

    f32x16 acc[4] = {};
    // x chunks first: registers already resident, overlap h-load latency
#pragma unroll
    for (int qx = 0; qx < 2; ++qx) {
      f16x8 a = __builtin_bit_cast(f16x8, xr[qx]);
      acc[0] = __builtin_amdgcn_mfma_f32_32x32x16_f16(a, __builtin_bit_cast(f16x8, Braw[0][16 + qx]), acc[0], 0, 0, 0);
      acc[1] = __builtin_amdgcn_mfma_f32_32x32x16_f16(a, __builtin_bit_cast(f16x8, Braw[1][16 + qx]), acc[1], 0, 0, 0);
      acc[2] = __builtin_amdgcn_mfma_f32_32x32x16_f16(a, __builtin_bit_cast(f16x8, Braw[2][16 + qx]), acc[2], 0, 0, 0);
      acc[3] = __builtin_amdgcn_mfma_f32_32x32x16_f16(a, __builtin_bit_cast(f16x8, Braw[3][16 + qx]), acc[3], 0, 0, 0);
    }
#pragma unroll
    for (int q = 0; q < 16; ++q) {
      f16x8 a = __builtin_bit_cast(f16x8, ah[q]);
      acc[0] = __builtin_amdgcn_mfma_f32_32x32x16_f16(a, __builtin_bit_cast(f16x8, Braw[0][q]), acc[0], 0, 0, 0);
      acc[1] = __builtin_amdgcn_mfma_f32_32x32x16_f16(a, __builtin_bit_cast(f16x8, Braw[1][q]), acc[1], 0, 0, 0);
      acc[2] = __builtin_amdgcn_mfma_f32_32x32x16_f16(a, __builtin_bit_cast(f16x8, Braw[2][q]), acc[2], 0, 0, 0);
      acc[3] = __builtin_amdgcn_mfma_f32_32x32x16_f16(a, __builtin_bit_cast(f16x8, Braw[3][q]), acc[3], 0, 0, 0);
    }

    // ---- cross-wave K reduction via LDS ----
#pragma unroll
    for (int n = 0; n < 4; ++n) {
#pragma unroll
      for (int c = 0; c < 4; ++c) {
        float4 v;
        v.x = acc[n][4 * c + 0]; v.y = acc[n][4 * c + 1];
        v.z = acc[n][4 * c + 2]; v.w = acc[n][4 * c + 3];
        redv[((w * 4u + (unsigned)n) * 4u + (unsigned)c) * 64u + l] = v;
      }
    }
    __syncthreads();

    float gv[4][4];
#pragma unroll
    for (int n = 0; n < 4; ++n) {
      float4 s; s.x = bias_v[n]; s.y = bias_v[n]; s.z = bias_v[n]; s.w = bias_v[n];
#pragma unroll
      for (int wo = 0; wo < 4; ++wo) {
        float4 v = redv[(((unsigned)wo * 4u + (unsigned)n) * 4u + w) * 64u + l];
        s.x += v.x; s.y += v.y; s.z += v.z; s.w += v.w;
      }
      gv[n][0] = s.x; gv[n][1] = s.y; gv[n][2] = s.z; gv[n][3] = s.w;
    }

    // ---- per-lane LSTM cell update (rows 8w+i+4hi); stage h to LDS ----
    const bool last = (t == 255u);
#pragma unroll
    for (int i = 0; i < 4; ++i) {
      float ig = 1.f / (1.f + __expf(-gv[0][i]));
      float fg = 1.f / (1.f + __expf(-gv[1][i]));
      float gg = tanhf(gv[2][i]);
      float og = 1.f / (1.f + __expf(-gv[3][i]));
      float cc = fg * c_st[i] + ig * gg;
      c_st[i] = cc;
      float hh = og * tanhf(cc);
      hst[(8u * w + (unsigned)i + 4u * hi) * 32u + lo5] = f2h(hh);
      if (last) sigh[soff[i]] = 1.f / (1.f + __expf(-hh));
    }

    if (!last) {
      __syncthreads();  // h staging tile complete
      // ---- coalesced 8B agent-coherent h store-out ----
      {
        u64 v = *(const u64*)(hst + srow * 32u + sseg * 4u);
        __hip_atomic_store((u64*)(hwr + sgoff), v, __ATOMIC_RELAXED, SCOPE_AGENT);
      }
      // prefetch next step's x fragments (independent of h; hides under drain)
      xb += 65536u;
      xr[0] = *(const int4*)(xbase + xb);
      xr[1] = *(const int4*)(xbase + xb + 32u);
      // __syncthreads lowering waits vmcnt(0): every thread's h store is ACKed
      // at the coherence point before any thread proceeds to the flag store.
      __syncthreads();
      // ---- RMW-free epoch-flag barrier ----
      if (tid == 0)
        __hip_atomic_store(&flags[cg], t + 1u, __ATOMIC_RELAXED, SCOPE_AGENT);
      if (tid < 64u) {
        const unsigned tgt = t + 1u;
        for (;;) {
          unsigned f = __hip_atomic_load(&flags[l & 31u], __ATOMIC_RELAXED, SCOPE_AGENT);
          if (__all(f >= tgt)) break;
          __builtin_amdgcn_s_sleep(1);
        }
      }
      __syncthreads();
    }

    const char* tmp = hrd; hrd = hwr; hwr = (char*)tmp;
  }
}

// out[b][o] = b_fc[o] + sum_k sigh[b][k] * W_fc[o][k]
__global__ void final_fc(const float* __restrict__ sigh, const float* __restrict__ W_fc,
                         const float* __restrict__ b_fc, float* __restrict__ out) {
  unsigned b = blockIdx.x;
  unsigned o = threadIdx.x;
  const float* hrow = sigh + (size_t)b * 1024u;
  const float* wrow = W_fc + (size_t)o * 1024u;
  float acc = b_fc[o];
#pragma unroll 8
  for (unsigned k = 0; k < 1024u; k += 4u) {
    float4 hv = *(const float4*)(hrow + k);
    float4 wv = *(const float4*)(wrow + k);
    acc += hv.x * wv.x + hv.y * wv.y + hv.z * wv.z + hv.w * wv.w;
  }
  out[b * 128u + o] = acc;
}

extern "C" void kernel_launch(void* const* d_in, const int* in_sizes, int n_in,
                              void* d_out, int out_size, void* d_ws, size_t ws_size,
                              hipStream_t stream) {
  (void)in_sizes; (void)n_in; (void)out_size; (void)ws_size;
  const float* x    = (const float*)d_in[0];
  const float* h0   = (const float*)d_in[1];
  const float* c0   = (const float*)d_in[2];
  const float* W_ih = (const float*)d_in[3];
  const float* W_hh = (const float*)d_in[4];
  const float* b_ih = (const float*)d_in[5];
  const float* b_hh = (const float*)d_in[6];
  const float* W_fc = (const float*)d_in[7];
  const float* b_fc = (const float*)d_in[8];

  char* ws = (char*)d_ws;
  unsigned short* wp   = (unsigned short*)(ws + WS_WP);
  float*          bias = (float*)(ws + WS_BIAS);
  unsigned short* xT   = (unsigned short*)(ws + WS_XT);
  unsigned short* hb0  = (unsigned short*)(ws + WS_HB0);
  unsigned short* hb1  = (unsigned short*)(ws + WS_HB1);
  float*          sigh = (float*)(ws + WS_SIGH);
  unsigned*       bar  = (unsigned*)(ws + WS_BAR);
  float*          out  = (float*)d_out;

  prep_pack<<<18432, 256, 0, stream>>>(W_ih, W_hh, b_ih, b_hh, wp, bias);
  prep_misc<<<32768, 256, 0, stream>>>(x, h0, xT, hb0, bar);
  lstm_main<<<256, 256, 67584, stream>>>(wp, bias, xT, hb0, hb1, c0, sigh, bar);
  final_fc<<<256, 128, 0, stream>>>(sigh, W_fc, b_fc, out);
}